// Round 1
// baseline (1205.303 us; speedup 1.0000x reference)
//
#include <hip/hip_runtime.h>

// HashEncoder forward (instant-ngp style), MI355X.
// Config (all compile-time): D=3, L=16, C=2, base=16, scale=2.0, 2^19 max params.
// Level l: res = 16<<l. Levels 0..2 dense (shift indexing), 3..15 hashed
// (level_size = 2^19 -> mask 0x7FFFF). Offsets: 0,4096,36864,299008,+524288...
//
// Mapping: one thread per (point, level). Lane layout: level = tid&15, so the
// 16 lanes of a point write 16 contiguous float2 -> coalesced 512B/wave stores.

static constexpr uint32_t P1 = 2654435761u;
static constexpr uint32_t P2 = 805459861u;

__global__ __launch_bounds__(256) void hashenc_fwd(
    const float* __restrict__ inp,
    const float* __restrict__ emb,
    float* __restrict__ out,
    int npoints)
{
    const uint32_t tid = blockIdx.x * 256u + threadIdx.x;
    const uint32_t p = tid >> 4;
    const uint32_t l = tid & 15u;
    if (p >= (uint32_t)npoints) return;

    // normalize [-1,1] -> [0,1]  (16 lanes per point read the same 12B: L1 broadcast)
    const float x01 = (inp[p * 3u + 0u] + 1.0f) * 0.5f;
    const float y01 = (inp[p * 3u + 1u] + 1.0f) * 0.5f;
    const float z01 = (inp[p * 3u + 2u] + 1.0f) * 0.5f;

    const uint32_t res = 16u << l;
    const float scale = (float)(res - 1u);

    const float posx = x01 * scale + 0.5f;
    const float posy = y01 * scale + 0.5f;
    const float posz = z01 * scale + 0.5f;

    const float fgx = floorf(posx);
    const float fgy = floorf(posy);
    const float fgz = floorf(posz);

    const float fx = posx - fgx;
    const float fy = posy - fgy;
    const float fz = posz - fgz;

    const uint32_t gx = (uint32_t)fgx;
    const uint32_t gy = (uint32_t)fgy;
    const uint32_t gz = (uint32_t)fgz;

    // level offset into the flat embedding table
    uint32_t off;
    if (l >= 3u)      off = 299008u + (l - 3u) * 524288u;
    else if (l == 2u) off = 36864u;
    else if (l == 1u) off = 4096u;
    else              off = 0u;

    const bool hashed = (l >= 3u);
    const uint32_t s = 4u + (hashed ? 0u : l);  // dense shift (log2 res), only used when !hashed

    const float wx[2] = {1.0f - fx, fx};
    const float wy[2] = {1.0f - fy, fy};
    const float wz[2] = {1.0f - fz, fz};

    float2 g[8];
    float  w[8];
#pragma unroll
    for (int c = 0; c < 8; ++c) {
        const uint32_t bx = (uint32_t)c & 1u;
        const uint32_t by = ((uint32_t)c >> 1) & 1u;
        const uint32_t bz = ((uint32_t)c >> 2) & 1u;
        const uint32_t cx = gx + bx;
        const uint32_t cy = gy + by;
        const uint32_t cz = gz + bz;
        const uint32_t hidx = (cx ^ (cy * P1) ^ (cz * P2)) & 524287u;
        const uint32_t didx = cx + (cy << s) + (cz << (2u * s));
        const uint32_t idx  = hashed ? hidx : didx;
        w[c] = wx[bx] * wy[by] * wz[bz];
        g[c] = *(const float2*)(emb + 2u * (off + idx));  // 8 independent loads in flight
    }

    float sx = 0.0f, sy = 0.0f;
#pragma unroll
    for (int c = 0; c < 8; ++c) {
        sx = fmaf(w[c], g[c].x, sx);
        sy = fmaf(w[c], g[c].y, sy);
    }

    *(float2*)(out + (size_t)p * 32u + (size_t)l * 2u) = make_float2(sx, sy);
}

extern "C" void kernel_launch(void* const* d_in, const int* in_sizes, int n_in,
                              void* d_out, int out_size, void* d_ws, size_t ws_size,
                              hipStream_t stream) {
    const float* inp = (const float*)d_in[0];   // [B,3] float32
    const float* emb = (const float*)d_in[1];   // [7114752,2] float32
    float* out = (float*)d_out;                 // [B,32] float32

    const int npoints = in_sizes[0] / 3;
    const int total   = npoints * 16;
    const int block   = 256;
    const int grid    = (total + block - 1) / block;

    hashenc_fwd<<<grid, block, 0, stream>>>(inp, emb, out, npoints);
}

// Round 2
// 674.202 us; speedup vs baseline: 1.7877x; 1.7877x over previous
//
#include <hip/hip_runtime.h>

// HashEncoder forward, R2: level-at-a-time L2 locality + bf16 table.
//
// Pass 0: convert fp32 embeddings -> packed bf16x2 table in ws (28.5 MB).
//         Hashed-level table shrinks 4 MiB -> 2 MiB, so one level (+ the
//         2-level dispatch-overlap window) fits a per-XCD 4 MiB L2.
// Pass 1: grid (points/256, 16); blockIdx.y = level. x-fastest dispatch =>
//         each XCD processes levels ~sequentially => gathers hit L2.
//         Results staged [level][point] (coalesced float2) in ws.
// Pass 2: transpose staging -> out[p][32].
// Fallback: if ws_size too small, R1 single-pass kernel.

static constexpr uint32_t P1 = 2654435761u;
static constexpr uint32_t P2 = 805459861u;
static constexpr uint32_t NPARAMS = 7114752u;   // total embedding rows (C=2)

// ---------- pass 0: fp32 -> packed bf16 ----------
__device__ inline uint32_t bf16_bits(float f) {  // RNE, returns bits in low 16
    uint32_t u = __float_as_uint(f);
    return (u + 0x7FFFu + ((u >> 16) & 1u)) >> 16;
}

__global__ __launch_bounds__(256) void convert_bf16(
    const float* __restrict__ emb, uint32_t* __restrict__ tab)
{
    // one thread packs 2 rows: float4 -> uint2
    const uint32_t i = blockIdx.x * 256u + threadIdx.x;   // float4 index
    const float4 v = ((const float4*)emb)[i];
    uint2 o;
    o.x = bf16_bits(v.x) | (bf16_bits(v.y) << 16);
    o.y = bf16_bits(v.z) | (bf16_bits(v.w) << 16);
    ((uint2*)tab)[i] = o;
}

// ---------- pass 1: one level per block ----------
__global__ __launch_bounds__(256) void enc_level(
    const float* __restrict__ inp,
    const uint32_t* __restrict__ tab,   // packed bf16x2 per row
    float2* __restrict__ stage,         // [16][np]
    int npoints)
{
    const uint32_t l = blockIdx.y;                    // wave-uniform level
    const uint32_t p = blockIdx.x * 256u + threadIdx.x;
    if (p >= (uint32_t)npoints) return;

    const float x01 = (inp[p * 3u + 0u] + 1.0f) * 0.5f;
    const float y01 = (inp[p * 3u + 1u] + 1.0f) * 0.5f;
    const float z01 = (inp[p * 3u + 2u] + 1.0f) * 0.5f;

    const uint32_t res = 16u << l;
    const float scale = (float)(res - 1u);

    const float posx = x01 * scale + 0.5f;
    const float posy = y01 * scale + 0.5f;
    const float posz = z01 * scale + 0.5f;

    const float fgx = floorf(posx), fgy = floorf(posy), fgz = floorf(posz);
    const float fx = posx - fgx, fy = posy - fgy, fz = posz - fgz;
    const uint32_t gx = (uint32_t)fgx, gy = (uint32_t)fgy, gz = (uint32_t)fgz;

    uint32_t off;
    if (l >= 3u)      off = 299008u + (l - 3u) * 524288u;
    else if (l == 2u) off = 36864u;
    else if (l == 1u) off = 4096u;
    else              off = 0u;
    const bool hashed = (l >= 3u);
    const uint32_t s = 4u + (hashed ? 0u : l);

    const float wx[2] = {1.0f - fx, fx};
    const float wy[2] = {1.0f - fy, fy};
    const float wz[2] = {1.0f - fz, fz};

    uint32_t gp[8];
    float    w[8];
#pragma unroll
    for (int c = 0; c < 8; ++c) {
        const uint32_t bx = (uint32_t)c & 1u;
        const uint32_t by = ((uint32_t)c >> 1) & 1u;
        const uint32_t bz = ((uint32_t)c >> 2) & 1u;
        const uint32_t cx = gx + bx, cy = gy + by, cz = gz + bz;
        const uint32_t hidx = (cx ^ (cy * P1) ^ (cz * P2)) & 524287u;
        const uint32_t didx = cx + (cy << s) + (cz << (2u * s));
        const uint32_t idx  = hashed ? hidx : didx;
        w[c]  = wx[bx] * wy[by] * wz[bz];
        gp[c] = tab[off + idx];                       // 8 independent 4B gathers
    }

    float sx = 0.0f, sy = 0.0f;
#pragma unroll
    for (int c = 0; c < 8; ++c) {
        const float ex = __uint_as_float(gp[c] << 16);
        const float ey = __uint_as_float(gp[c] & 0xFFFF0000u);
        sx = fmaf(w[c], ex, sx);
        sy = fmaf(w[c], ey, sy);
    }

    stage[(size_t)l * (uint32_t)npoints + p] = make_float2(sx, sy);
}

// ---------- pass 2: [16][np] -> [np][32] ----------
__global__ __launch_bounds__(256) void transpose_out(
    const float2* __restrict__ stage, float* __restrict__ out, int npoints)
{
    const uint32_t p = blockIdx.x * 256u + threadIdx.x;
    if (p >= (uint32_t)npoints) return;
    float2 v[16];
#pragma unroll
    for (int l = 0; l < 16; ++l)
        v[l] = stage[(size_t)l * (uint32_t)npoints + p];   // coalesced per level
    float4* o = (float4*)(out + (size_t)p * 32u);
#pragma unroll
    for (int k = 0; k < 8; ++k)
        o[k] = make_float4(v[2 * k].x, v[2 * k].y, v[2 * k + 1].x, v[2 * k + 1].y);
}

// ---------- fallback: R1 single-pass ----------
__global__ __launch_bounds__(256) void hashenc_fwd(
    const float* __restrict__ inp, const float* __restrict__ emb,
    float* __restrict__ out, int npoints)
{
    const uint32_t tid = blockIdx.x * 256u + threadIdx.x;
    const uint32_t p = tid >> 4, l = tid & 15u;
    if (p >= (uint32_t)npoints) return;
    const float x01 = (inp[p * 3u + 0u] + 1.0f) * 0.5f;
    const float y01 = (inp[p * 3u + 1u] + 1.0f) * 0.5f;
    const float z01 = (inp[p * 3u + 2u] + 1.0f) * 0.5f;
    const uint32_t res = 16u << l;
    const float scale = (float)(res - 1u);
    const float posx = x01 * scale + 0.5f, posy = y01 * scale + 0.5f, posz = z01 * scale + 0.5f;
    const float fgx = floorf(posx), fgy = floorf(posy), fgz = floorf(posz);
    const float fx = posx - fgx, fy = posy - fgy, fz = posz - fgz;
    const uint32_t gx = (uint32_t)fgx, gy = (uint32_t)fgy, gz = (uint32_t)fgz;
    uint32_t off;
    if (l >= 3u)      off = 299008u + (l - 3u) * 524288u;
    else if (l == 2u) off = 36864u;
    else if (l == 1u) off = 4096u;
    else              off = 0u;
    const bool hashed = (l >= 3u);
    const uint32_t s = 4u + (hashed ? 0u : l);
    const float wx[2] = {1.0f - fx, fx}, wy[2] = {1.0f - fy, fy}, wz[2] = {1.0f - fz, fz};
    float2 g[8]; float w[8];
#pragma unroll
    for (int c = 0; c < 8; ++c) {
        const uint32_t bx = (uint32_t)c & 1u, by = ((uint32_t)c >> 1) & 1u, bz = ((uint32_t)c >> 2) & 1u;
        const uint32_t cx = gx + bx, cy = gy + by, cz = gz + bz;
        const uint32_t hidx = (cx ^ (cy * P1) ^ (cz * P2)) & 524287u;
        const uint32_t didx = cx + (cy << s) + (cz << (2u * s));
        const uint32_t idx  = hashed ? hidx : didx;
        w[c] = wx[bx] * wy[by] * wz[bz];
        g[c] = *(const float2*)(emb + 2u * (off + idx));
    }
    float sx = 0.0f, sy = 0.0f;
#pragma unroll
    for (int c = 0; c < 8; ++c) { sx = fmaf(w[c], g[c].x, sx); sy = fmaf(w[c], g[c].y, sy); }
    *(float2*)(out + (size_t)p * 32u + (size_t)l * 2u) = make_float2(sx, sy);
}

extern "C" void kernel_launch(void* const* d_in, const int* in_sizes, int n_in,
                              void* d_out, int out_size, void* d_ws, size_t ws_size,
                              hipStream_t stream) {
    const float* inp = (const float*)d_in[0];
    const float* emb = (const float*)d_in[1];
    float* out = (float*)d_out;
    const int npoints = in_sizes[0] / 3;

    const size_t tab_bytes = (size_t)NPARAMS * 4u;              // 28,459,008 (4K-aligned)
    const size_t stage_bytes = (size_t)npoints * 16u * 8u;      // 134,217,728
    const size_t need = tab_bytes + stage_bytes;

    if (ws_size >= need && (npoints & 255) == 0) {
        uint32_t* tab = (uint32_t*)d_ws;
        float2* stage = (float2*)((char*)d_ws + tab_bytes);

        const int conv_units = (int)(NPARAMS * 2u / 4u);        // 3,557,376 float4s
        convert_bf16<<<(conv_units + 255) / 256, 256, 0, stream>>>(emb, tab);

        dim3 g1(npoints / 256, 16);
        enc_level<<<g1, 256, 0, stream>>>(inp, tab, stage, npoints);

        transpose_out<<<npoints / 256, 256, 0, stream>>>(stage, out, npoints);
    } else {
        const int total = npoints * 16;
        hashenc_fwd<<<(total + 255) / 256, 256, 0, stream>>>(inp, emb, out, npoints);
    }
}

// Round 3
// 584.455 us; speedup vs baseline: 2.0623x; 1.1536x over previous
//
#include <hip/hip_runtime.h>

// HashEncoder forward, R3.
// - Pass 0: fp32 -> packed bf16x2 table (28.5 MB; hashed level = 2 MiB, L2-resident).
// - Pass 1 (enc_level): one level per blockIdx.y; parity pair-load: x-prime==1 so
//   for even gx both x-corners of a (y,z) pair are an aligned uint2 {idx, idx^1}
//   (dense levels too: didx parity == gx parity, s>=4). 4x 8B pair loads + 4x 4B
//   odd-gx-only loads (exec-masked) => avg 6 line-requests/point vs 8.
// - Pass 2: LDS-tiled transpose [16][np] -> [np][32], coalesced both sides.

static constexpr uint32_t P1 = 2654435761u;
static constexpr uint32_t P2 = 805459861u;
static constexpr uint32_t NPARAMS = 7114752u;
static constexpr uint32_t HMASK = 524287u;

// ---------- pass 0 ----------
__device__ inline uint32_t bf16_bits(float f) {
    uint32_t u = __float_as_uint(f);
    return (u + 0x7FFFu + ((u >> 16) & 1u)) >> 16;
}

__global__ __launch_bounds__(256) void convert_bf16(
    const float* __restrict__ emb, uint32_t* __restrict__ tab)
{
    const uint32_t i = blockIdx.x * 256u + threadIdx.x;   // float4 index
    const float4 v = ((const float4*)emb)[i];
    uint2 o;
    o.x = bf16_bits(v.x) | (bf16_bits(v.y) << 16);
    o.y = bf16_bits(v.z) | (bf16_bits(v.w) << 16);
    ((uint2*)tab)[i] = o;
}

// ---------- pass 1 ----------
__global__ __launch_bounds__(256) void enc_level(
    const float* __restrict__ inp,
    const uint32_t* __restrict__ tab,   // packed bf16x2 per row
    float2* __restrict__ stage,         // [16][np]
    int npoints)
{
    const uint32_t l = blockIdx.y;
    const uint32_t p = blockIdx.x * 256u + threadIdx.x;
    if (p >= (uint32_t)npoints) return;

    const float x01 = (inp[p * 3u + 0u] + 1.0f) * 0.5f;
    const float y01 = (inp[p * 3u + 1u] + 1.0f) * 0.5f;
    const float z01 = (inp[p * 3u + 2u] + 1.0f) * 0.5f;

    const uint32_t res = 16u << l;
    const float scale = (float)(res - 1u);

    const float posx = x01 * scale + 0.5f;
    const float posy = y01 * scale + 0.5f;
    const float posz = z01 * scale + 0.5f;

    const float fgx = floorf(posx), fgy = floorf(posy), fgz = floorf(posz);
    const float fx = posx - fgx, fy = posy - fgy, fz = posz - fgz;
    const uint32_t gx = (uint32_t)fgx, gy = (uint32_t)fgy, gz = (uint32_t)fgz;

    uint32_t off;
    if (l >= 3u)      off = 299008u + (l - 3u) * 524288u;
    else if (l == 2u) off = 36864u;
    else if (l == 1u) off = 4096u;
    else              off = 0u;
    const bool hashed = (l >= 3u);
    const uint32_t s = 4u + (hashed ? 0u : l);

    const float wx0 = 1.0f - fx, wx1 = fx;
    const float wy[2] = {1.0f - fy, fy};
    const float wz[2] = {1.0f - fz, fz};

    // per-(y,z) index contributions
    uint32_t yzc[4];
    if (hashed) {
        const uint32_t hy0 = gy * P1, hy1 = hy0 + P1;
        const uint32_t hz0 = gz * P2, hz1 = hz0 + P2;
        yzc[0] = hy0 ^ hz0; yzc[1] = hy1 ^ hz0;
        yzc[2] = hy0 ^ hz1; yzc[3] = hy1 ^ hz1;
    } else {
        const uint32_t dy0 = gy << s, dy1 = dy0 + (1u << s);
        const uint32_t dz0 = gz << (2u * s), dz1 = dz0 + (1u << (2u * s));
        yzc[0] = dy0 + dz0; yzc[1] = dy1 + dz0;
        yzc[2] = dy0 + dz1; yzc[3] = dy1 + dz1;
    }

    const bool gx_odd = (gx & 1u) != 0u;

    uint32_t idxA[4], idxB[4];
#pragma unroll
    for (int c = 0; c < 4; ++c) {
        if (hashed) {
            idxA[c] = (gx ^ yzc[c]) & HMASK;
            idxB[c] = ((gx + 1u) ^ yzc[c]) & HMASK;
        } else {
            idxA[c] = gx + yzc[c];
            idxB[c] = idxA[c] + 1u;
        }
    }

    // pair loads (always; covers both x-corners when gx even)
    uint2 pr[4];
#pragma unroll
    for (int c = 0; c < 4; ++c)
        pr[c] = *(const uint2*)(tab + off + (idxA[c] & ~1u));

    // odd-gx extra loads, exec-masked so even lanes issue no requests
    uint32_t vBo[4];
    if (gx_odd) {
#pragma unroll
        for (int c = 0; c < 4; ++c)
            vBo[c] = tab[off + idxB[c]];
    }

    float sx = 0.0f, sy = 0.0f;
#pragma unroll
    for (int c = 0; c < 4; ++c) {
        const uint32_t lo = idxA[c] & 1u;
        const uint32_t vA = lo ? pr[c].y : pr[c].x;
        const uint32_t vBe = lo ? pr[c].x : pr[c].y;   // idxA^1, valid iff gx even
        const uint32_t vB = gx_odd ? vBo[c] : vBe;
        const float wyz = wy[c & 1] * wz[c >> 1];
        const float eAx = __uint_as_float(vA << 16);
        const float eAy = __uint_as_float(vA & 0xFFFF0000u);
        const float eBx = __uint_as_float(vB << 16);
        const float eBy = __uint_as_float(vB & 0xFFFF0000u);
        sx = fmaf(wyz, fmaf(wx0, eAx, wx1 * eBx), sx);
        sy = fmaf(wyz, fmaf(wx0, eAy, wx1 * eBy), sy);
    }

    stage[(size_t)l * (uint32_t)npoints + p] = make_float2(sx, sy);
}

// ---------- pass 2: LDS-tiled transpose ----------
__global__ __launch_bounds__(256) void transpose_out(
    const float2* __restrict__ stage, float4* __restrict__ out4, int npoints)
{
    __shared__ float2 t[256][17];   // +1 pad: 2 lanes/bank on load phase (free)
    const uint32_t p0 = blockIdx.x * 256u;
    const uint32_t tid = threadIdx.x;

#pragma unroll
    for (int l = 0; l < 16; ++l)
        t[tid][l] = stage[(size_t)l * (uint32_t)npoints + p0 + tid];  // coalesced 2KB
    __syncthreads();

#pragma unroll
    for (int k = 0; k < 8; ++k) {
        const uint32_t f = (uint32_t)k * 256u + tid;
        const uint32_t p = f >> 3, c = f & 7u;
        const float2 a = t[p][2u * c];
        const float2 b = t[p][2u * c + 1u];
        out4[(size_t)(p0 + p) * 8u + c] = make_float4(a.x, a.y, b.x, b.y);  // coalesced 4KB
    }
}

// ---------- fallback: single-pass (R1) ----------
__global__ __launch_bounds__(256) void hashenc_fwd(
    const float* __restrict__ inp, const float* __restrict__ emb,
    float* __restrict__ out, int npoints)
{
    const uint32_t tid = blockIdx.x * 256u + threadIdx.x;
    const uint32_t p = tid >> 4, l = tid & 15u;
    if (p >= (uint32_t)npoints) return;
    const float x01 = (inp[p * 3u + 0u] + 1.0f) * 0.5f;
    const float y01 = (inp[p * 3u + 1u] + 1.0f) * 0.5f;
    const float z01 = (inp[p * 3u + 2u] + 1.0f) * 0.5f;
    const uint32_t res = 16u << l;
    const float scale = (float)(res - 1u);
    const float posx = x01 * scale + 0.5f, posy = y01 * scale + 0.5f, posz = z01 * scale + 0.5f;
    const float fgx = floorf(posx), fgy = floorf(posy), fgz = floorf(posz);
    const float fx = posx - fgx, fy = posy - fgy, fz = posz - fgz;
    const uint32_t gx = (uint32_t)fgx, gy = (uint32_t)fgy, gz = (uint32_t)fgz;
    uint32_t off;
    if (l >= 3u)      off = 299008u + (l - 3u) * 524288u;
    else if (l == 2u) off = 36864u;
    else if (l == 1u) off = 4096u;
    else              off = 0u;
    const bool hashed = (l >= 3u);
    const uint32_t s = 4u + (hashed ? 0u : l);
    const float wx[2] = {1.0f - fx, fx}, wy[2] = {1.0f - fy, fy}, wz[2] = {1.0f - fz, fz};
    float2 g[8]; float w[8];
#pragma unroll
    for (int c = 0; c < 8; ++c) {
        const uint32_t bx = (uint32_t)c & 1u, by = ((uint32_t)c >> 1) & 1u, bz = ((uint32_t)c >> 2) & 1u;
        const uint32_t cx = gx + bx, cy = gy + by, cz = gz + bz;
        const uint32_t hidx = (cx ^ (cy * P1) ^ (cz * P2)) & HMASK;
        const uint32_t didx = cx + (cy << s) + (cz << (2u * s));
        const uint32_t idx  = hashed ? hidx : didx;
        w[c] = wx[bx] * wy[by] * wz[bz];
        g[c] = *(const float2*)(emb + 2u * (off + idx));
    }
    float sx = 0.0f, sy = 0.0f;
#pragma unroll
    for (int c = 0; c < 8; ++c) { sx = fmaf(w[c], g[c].x, sx); sy = fmaf(w[c], g[c].y, sy); }
    *(float2*)(out + (size_t)p * 32u + (size_t)l * 2u) = make_float2(sx, sy);
}

extern "C" void kernel_launch(void* const* d_in, const int* in_sizes, int n_in,
                              void* d_out, int out_size, void* d_ws, size_t ws_size,
                              hipStream_t stream) {
    const float* inp = (const float*)d_in[0];
    const float* emb = (const float*)d_in[1];
    float* out = (float*)d_out;
    const int npoints = in_sizes[0] / 3;

    const size_t tab_bytes = (size_t)NPARAMS * 4u;
    const size_t stage_bytes = (size_t)npoints * 16u * 8u;
    const size_t need = tab_bytes + stage_bytes;

    if (ws_size >= need && (npoints & 255) == 0) {
        uint32_t* tab = (uint32_t*)d_ws;
        float2* stage = (float2*)((char*)d_ws + tab_bytes);

        const int conv_units = (int)(NPARAMS * 2u / 4u);
        convert_bf16<<<(conv_units + 255) / 256, 256, 0, stream>>>(emb, tab);

        dim3 g1(npoints / 256, 16);
        enc_level<<<g1, 256, 0, stream>>>(inp, tab, stage, npoints);

        transpose_out<<<npoints / 256, 256, 0, stream>>>(stage, (float4*)out, npoints);
    } else {
        const int total = npoints * 16;
        hashenc_fwd<<<(total + 255) / 256, 256, 0, stream>>>(inp, emb, out, npoints);
    }
}